// Round 1
// baseline (1119.948 us; speedup 1.0000x reference)
//
#include <hip/hip_runtime.h>

#define NS 48
#define NV 10
#define X1DIM 108      // NS + 6*NV
#define WNUM 4344
#define OUTDIM 156     // 2*NS + 6*NV

// per-z weight offsets (floats)
#define OFF_W00  0
#define OFF_W01  2304
#define OFF_W10  2784
#define OFF_W110 2884
#define OFF_W112 3364
#define OFF_W12  3464
#define OFF_W20  3564
#define OFF_W211 3664
#define OFF_W213 3764
#define OFF_W22  4244

// normalization constants
#define N0E  0.131306432859723f   // sqrt(1/58)
#define N1O  0.196116135138184f   // sqrt(3/78)
#define N1E  0.316227766016838f   // sqrt(1/10)
#define N0O  0.316227766016838f   // sqrt(1/10)
#define ISQ3 0.577350269189626f   // 1/sqrt(3)
#define ISQ6 0.408248290463863f   // 1/sqrt(6)
#define S10  0.316227766016838f   // 1/sqrt(10)
#define S30  0.182574185835055f   // 1/sqrt(30)

__global__ __launch_bounds__(256) void tp_third_kernel(
    const float* __restrict__ x1g, const float* __restrict__ x2g,
    const float* __restrict__ wg, float* __restrict__ outg)
{
    const int z = blockIdx.x;
    const int t = threadIdx.x;

    __shared__ float w[WNUM];
    __shared__ float sx1[X1DIM];
    __shared__ float sx2[9];
    __shared__ float s01[NV];          // sum_u x1_0e[u]*w01[u,w]
    __shared__ float d1o[NV], d1e[NV]; // dot(x1_1x[u], x2_1o)
    __shared__ float t112[NV][3], t12[NV][3], t211[NV][3], t22[NV][3];

    // ---- Phase 1: coalesced global -> LDS staging ----
    {
        const float4* wsrc = (const float4*)(wg + (size_t)z * WNUM);
        float4* wdst = (float4*)w;
        #pragma unroll
        for (int i = 0; i < 5; ++i) {
            int idx = t + i * 256;
            if (idx < WNUM / 4) wdst[idx] = wsrc[idx];
        }
        if (t < X1DIM / 4)
            ((float4*)sx1)[t] = ((const float4*)(x1g + (size_t)z * X1DIM))[t];
        if (t >= 32 && t < 41)
            sx2[t - 32] = x2g[(size_t)z * 9 + (t - 32)];
    }
    __syncthreads();

    // ---- Phase 2: small intermediates ----
    if (t < 10) {
        float acc = 0.f;
        #pragma unroll
        for (int u = 0; u < NS; ++u) acc += sx1[u] * w[OFF_W01 + u * NV + t];
        s01[t] = acc;
    } else if (t < 20) {
        int u = t - 10;
        d1o[u] = sx1[48 + u*3]     * sx2[1]
               + sx1[48 + u*3 + 1] * sx2[2]
               + sx1[48 + u*3 + 2] * sx2[3];
    } else if (t < 30) {
        int u = t - 20;
        d1e[u] = sx1[78 + u*3]     * sx2[1]
               + sx1[78 + u*3 + 1] * sx2[2]
               + sx1[78 + u*3 + 2] * sx2[3];
    } else if (t < 40) {
        int u = t - 30;  // t112 = cross(x1_1o[u], x2_1o)/sqrt(6)
        float a0 = sx1[48+u*3], a1 = sx1[48+u*3+1], a2 = sx1[48+u*3+2];
        float b0 = sx2[1], b1 = sx2[2], b2 = sx2[3];
        t112[u][0] = ISQ6 * (a1*b2 - a2*b1);
        t112[u][1] = ISQ6 * (a2*b0 - a0*b2);
        t112[u][2] = ISQ6 * (a0*b1 - a1*b0);
    } else if (t < 50) {
        int u = t - 40;  // t12 = W3J121 contraction of (x1_1o[u], x2_2e)
        float a0 = sx1[48+u*3], a1 = sx1[48+u*3+1], a2 = sx1[48+u*3+2];
        float b0 = sx2[4], b1 = sx2[5], b2 = sx2[6], b3 = sx2[7], b4 = sx2[8];
        t12[u][0] = S10*(a2*b0 + a1*b1 - a0*b4) - S30*a0*b2;
        t12[u][1] = S10*(a2*b3 + a0*b1) + 2.f*S30*a1*b2;
        t12[u][2] = S10*(a2*b4 + a0*b0 + a1*b3) - S30*a2*b2;
    } else if (t < 60) {
        int u = t - 50;  // t211 = cross(x1_1e[u], x2_1o)/sqrt(6)
        float a0 = sx1[78+u*3], a1 = sx1[78+u*3+1], a2 = sx1[78+u*3+2];
        float b0 = sx2[1], b1 = sx2[2], b2 = sx2[3];
        t211[u][0] = ISQ6 * (a1*b2 - a2*b1);
        t211[u][1] = ISQ6 * (a2*b0 - a0*b2);
        t211[u][2] = ISQ6 * (a0*b1 - a1*b0);
    } else if (t < 70) {
        int u = t - 60;  // t22 = W3J121 contraction of (x1_1e[u], x2_2e)
        float a0 = sx1[78+u*3], a1 = sx1[78+u*3+1], a2 = sx1[78+u*3+2];
        float b0 = sx2[4], b1 = sx2[5], b2 = sx2[6], b3 = sx2[7], b4 = sx2[8];
        t22[u][0] = S10*(a2*b0 + a1*b1 - a0*b4) - S30*a0*b2;
        t22[u][1] = S10*(a2*b3 + a0*b1) + 2.f*S30*a1*b2;
        t22[u][2] = S10*(a2*b4 + a0*b0 + a1*b3) - S30*a2*b2;
    }
    __syncthreads();

    // ---- Phase 3: one output element per thread ----
    if (t < OUTDIM) {
        float res;
        if (t < 48) {
            // r0e[w]
            int wi = t;
            float acc = 0.f;
            #pragma unroll
            for (int u = 0; u < NS; ++u) acc += sx1[u] * w[OFF_W00 + u * NS + wi];
            acc *= sx2[0];
            float acc2 = 0.f;
            #pragma unroll
            for (int u = 0; u < NV; ++u) acc2 += d1o[u] * w[OFF_W110 + u * NS + wi];
            res = N0E * (acc + ISQ3 * acc2);
        } else if (t < 78) {
            // r1o[w,k]
            int o = t - 48, wi = o / 3, k = o % 3;
            float acc10 = 0.f, acc12 = 0.f, acc211 = 0.f;
            #pragma unroll
            for (int u = 0; u < NV; ++u) {
                acc10  += sx1[48 + u*3 + k] * w[OFF_W10  + u * NV + wi];
                acc12  += t12[u][k]         * w[OFF_W12  + u * NV + wi];
                acc211 += t211[u][k]        * w[OFF_W211 + u * NV + wi];
            }
            res = N1O * (ISQ3 * (sx2[1 + k] * s01[wi] + sx2[0] * acc10)
                         + acc12 + acc211);
        } else if (t < 108) {
            // r1e[w,k]
            int o = t - 78, wi = o / 3, k = o % 3;
            float acc112 = 0.f, acc20 = 0.f, acc22 = 0.f;
            #pragma unroll
            for (int u = 0; u < NV; ++u) {
                acc112 += t112[u][k]        * w[OFF_W112 + u * NV + wi];
                acc20  += sx1[78 + u*3 + k] * w[OFF_W20  + u * NV + wi];
                acc22  += t22[u][k]         * w[OFF_W22  + u * NV + wi];
            }
            res = N1E * (acc112 + ISQ3 * sx2[0] * acc20 + acc22);
        } else {
            // r0o[w]
            int wi = t - 108;
            float acc = 0.f;
            #pragma unroll
            for (int u = 0; u < NV; ++u) acc += d1e[u] * w[OFF_W213 + u * NS + wi];
            res = N0O * ISQ3 * acc;
        }
        outg[(size_t)z * OUTDIM + t] = res;
    }
}

extern "C" void kernel_launch(void* const* d_in, const int* in_sizes, int n_in,
                              void* d_out, int out_size, void* d_ws, size_t ws_size,
                              hipStream_t stream) {
    const float* x1 = (const float*)d_in[0];
    const float* x2 = (const float*)d_in[1];
    const float* wt = (const float*)d_in[2];
    float* out = (float*)d_out;
    const int Z = in_sizes[0] / X1DIM;
    tp_third_kernel<<<Z, 256, 0, stream>>>(x1, x2, wt, out);
}